// Round 9
// baseline (303.921 us; speedup 1.0000x reference)
//
#include <hip/hip_runtime.h>
#include <math.h>

#define CONF_T 0.05f
#define NEGF  -1e10f
#define NCLS 16
#define TDET 100
#define CAP 4096
#define MSEL 640
#define NSLOT 10            // MSEL/64
#define MTOT (NCLS*TDET)    // 1600

// DPP-based combine: (max score, tie -> min j). Lattice op: associative,
// commutative, idempotent => over-inclusive row masks / self-combine safe.
template<int CTRL>
__device__ __forceinline__ void dpp_comb(float& s, int& j) {
  int si_ = __builtin_amdgcn_update_dpp(__float_as_int(s), __float_as_int(s),
                                        CTRL, 0xf, 0xf, false);
  int ji_ = __builtin_amdgcn_update_dpp(j, j, CTRL, 0xf, 0xf, false);
  float si = __int_as_float(si_);
  bool take = (si > s) || (si == s && ji_ < j);
  s = take ? si : s;
  j = take ? ji_ : j;
}
template<int CTRL>
__device__ __forceinline__ void dpp_max1(float& s) {
  int si_ = __builtin_amdgcn_update_dpp(__float_as_int(s), __float_as_int(s),
                                        CTRL, 0xf, 0xf, false);
  s = fmaxf(s, __int_as_float(si_));
}
#define ROW_SHR1  0x111
#define ROW_SHR2  0x112
#define ROW_SHR4  0x114
#define ROW_SHR8  0x118
#define ROW_BC15  0x142
#define ROW_BC31  0x143

__device__ __forceinline__ void wave_comb64(float& s, int& j) {
  dpp_comb<ROW_SHR1>(s, j);
  dpp_comb<ROW_SHR2>(s, j);
  dpp_comb<ROW_SHR4>(s, j);
  dpp_comb<ROW_SHR8>(s, j);
  dpp_comb<ROW_BC15>(s, j);
  dpp_comb<ROW_BC31>(s, j);
}
__device__ __forceinline__ void wave_fmax64(float& s) {
  dpp_max1<ROW_SHR1>(s);
  dpp_max1<ROW_SHR2>(s);
  dpp_max1<ROW_SHR4>(s);
  dpp_max1<ROW_SHR8>(s);
  dpp_max1<ROW_BC15>(s);
  dpp_max1<ROW_BC31>(s);
}
__device__ __forceinline__ float rl_f(float v, int l) {
  return __int_as_float(__builtin_amdgcn_readlane(__float_as_int(v), l));
}

// ---------------- K1: decode boxes + class/score + per-chunk class counts ----------------
__global__ __launch_bounds__(256) void k_decode(
    const float* __restrict__ pred, const float* __restrict__ anch,
    float* __restrict__ boxes, float* __restrict__ score, int* __restrict__ cls,
    int* __restrict__ counts, int N, int nchunk)
{
  #pragma clang fp contract(off)
  const int b = blockIdx.x / nchunk;
  const int chunk = blockIdx.x % nchunk;
  const int t = threadIdx.x;
  const int n = chunk * 256 + t;

  __shared__ int hist[NCLS];
  if (t < NCLS) hist[t] = 0;
  __syncthreads();

  int v = -1;
  if (n < N) {
    const size_t i = (size_t)b * N + n;
    const float4* p4 = reinterpret_cast<const float4*>(pred + i * 20);
    float4 v0 = p4[0], v1 = p4[1], v2 = p4[2], v3 = p4[3], v4 = p4[4];
    float4 a = reinterpret_cast<const float4*>(anch)[n];  // cx, cy, w, h
    float xx = v0.x * a.z + a.x;
    float yy = v0.y * a.w + a.y;
    float wx = expf(v0.z) * a.z;
    float wy = expf(v0.w) * a.w;
    float hx = 0.5f * wx, hy = 0.5f * wy;
    float4 bx;
    bx.x = xx - hx; bx.y = yy - hy; bx.z = xx + hx; bx.w = yy + hy;
    reinterpret_cast<float4*>(boxes)[i] = bx;

    float lg[NCLS] = {v1.x, v1.y, v1.z, v1.w, v2.x, v2.y, v2.z, v2.w,
                      v3.x, v3.y, v3.z, v3.w, v4.x, v4.y, v4.z, v4.w};
    float best = -1.0f; int bi = 0;
    #pragma unroll
    for (int c = 0; c < NCLS; ++c) {
      float s = 1.0f / (1.0f + expf(-lg[c]));
      if (s > best) { best = s; bi = c; }
    }
    score[i] = best;
    v = (best >= CONF_T) ? bi : -1;
    cls[i] = v;
  }

  int lane = t & 63;
  #pragma unroll
  for (int c = 0; c < NCLS; ++c) {
    unsigned long long bl = __ballot(v == c);
    if (lane == 0 && bl) atomicAdd(&hist[c], __popcll(bl));
  }
  __syncthreads();
  if (t < NCLS) counts[(b * NCLS + t) * nchunk + chunk] = hist[t];
}

// ---------------- K2: per-(b,c) exclusive scan over chunk counts ----------------
__global__ __launch_bounds__(256) void k_scan(
    const int* __restrict__ counts, int* __restrict__ offs, int* __restrict__ ktot,
    int nchunk)
{
  const int bc = blockIdx.x;
  const int t = threadIdx.x;
  __shared__ int c_[256];
  __shared__ int o_[257];
  if (t < nchunk) c_[t] = counts[bc * nchunk + t];
  __syncthreads();
  if (t == 0) {
    int run = 0;
    for (int i = 0; i < nchunk; ++i) { o_[i] = run; run += c_[i]; }
    o_[nchunk] = run;
  }
  __syncthreads();
  if (t < nchunk) offs[bc * nchunk + t] = o_[t];
  if (t == 0) ktot[bc] = o_[nchunk];
}

// ---------------- K3: stable parallel scatter into per-(b,c) candidate lists ----------------
__global__ __launch_bounds__(256) void k_scatter(
    const float* __restrict__ score, const int* __restrict__ cls,
    const float* __restrict__ boxes, const int* __restrict__ offs,
    float* __restrict__ cand_sc, float* __restrict__ cand_bx,
    int N, int nchunk)
{
  const int b = blockIdx.x / nchunk;
  const int chunk = blockIdx.x % nchunk;
  const int t = threadIdx.x;
  const int n = chunk * 256 + t;

  __shared__ int wcnt[4][NCLS];
  int v = (n < N) ? cls[(size_t)b * N + n] : -1;
  int lane = t & 63, w = t >> 6;
  int myrank = 0;
  #pragma unroll
  for (int c = 0; c < NCLS; ++c) {
    unsigned long long bl = __ballot(v == c);
    if (lane == 0) wcnt[w][c] = __popcll(bl);
    if (v == c) myrank = __popcll(bl & ((1ull << lane) - 1ull));
  }
  __syncthreads();
  if (v >= 0) {
    int pre = 0;
    #pragma unroll
    for (int i = 0; i < 4; ++i) if (i < w) pre += wcnt[i][v];
    int pos = offs[(b * NCLS + v) * nchunk + chunk] + pre + myrank;
    if (pos < CAP) {
      int bc = b * NCLS + v;
      cand_sc[(size_t)bc * CAP + pos] = score[(size_t)b * N + n];
      reinterpret_cast<float4*>(cand_bx)[(size_t)bc * CAP + pos] =
          reinterpret_cast<const float4*>(boxes)[(size_t)b * N + n];
    }
  }
}

// ---------------- K4: per-(b,c) top-MSEL selection (whole quantization bins) ----------------
// Keeps all entries whose score-bin >= T where T = min bin with cntGE(T) <= MSEL.
// thr = max excluded score (strictly below every kept score's bin). Order kept.
__global__ __launch_bounds__(1024) void k_select(
    const float* __restrict__ cand_sc, const float* __restrict__ cand_bx,
    const int* __restrict__ ktot,
    float* __restrict__ c2_sc, float* __restrict__ c2_bx,
    int* __restrict__ kcnt, float* __restrict__ thrv)
{
  const int bc = blockIdx.x;
  const int t = threadIdx.x;
  __shared__ int hist[4096];
  __shared__ int ss[1024];
  __shared__ int s_T;
  __shared__ int s_thrbits;
  __shared__ int s_wtot[16];

  int K = ktot[bc]; if (K > CAP) K = CAP;
  for (int i = t; i < 4096; i += 1024) hist[i] = 0;
  if (t == 0) { s_T = 4096; s_thrbits = 0; }
  __syncthreads();

  float sc[4]; int key[4];
  #pragma unroll
  for (int k = 0; k < 4; ++k) {
    int j = k * 1024 + t;
    if (j < K) {
      sc[k] = cand_sc[(size_t)bc * CAP + j];
      int bits = __float_as_int(sc[k]);
      int kk = (bits >> 11) - 0x7E000;          // [0.5,1.0) -> 0..4095, monotone
      kk = kk < 0 ? 0 : (kk > 4095 ? 4095 : kk);
      key[k] = kk;
      atomicAdd(&hist[kk], 1);
    } else { key[k] = -1; sc[k] = 0.0f; }
  }
  __syncthreads();

  int loc = hist[4 * t] + hist[4 * t + 1] + hist[4 * t + 2] + hist[4 * t + 3];
  ss[t] = loc;
  __syncthreads();
  for (int d = 1; d < 1024; d <<= 1) {
    int v = ss[t];
    int a = (t + d < 1024) ? ss[t + d] : 0;
    __syncthreads();
    ss[t] = v + a;
    __syncthreads();
  }
  {
    int h0 = hist[4 * t], h1 = hist[4 * t + 1], h2 = hist[4 * t + 2];
    int c0 = ss[t];           // cntGE(4t)
    int c1 = c0 - h0, c2v = c1 - h1, c3 = c2v - h2;
    int cand = 0x7fffffff;
    if      (c0  <= MSEL) cand = 4 * t;
    else if (c1  <= MSEL) cand = 4 * t + 1;
    else if (c2v <= MSEL) cand = 4 * t + 2;
    else if (c3  <= MSEL) cand = 4 * t + 3;
    if (cand != 0x7fffffff) atomicMin(&s_T, cand);
  }
  __syncthreads();
  const int T = s_T;
  #pragma unroll
  for (int k = 0; k < 4; ++k)
    if (key[k] >= 0 && key[k] < T) atomicMax(&s_thrbits, __float_as_int(sc[k]));
  __syncthreads();

  // stable compaction of kept entries (order preserved)
  int running = 0;
  #pragma unroll
  for (int k = 0; k < 4; ++k) {
    int j = k * 1024 + t;
    bool v = (key[k] >= 0) && (key[k] >= T);
    unsigned long long bl = __ballot(v);
    int lane = t & 63, w = t >> 6;
    if (lane == 0) s_wtot[w] = __popcll(bl);
    __syncthreads();
    int off = 0, tot = 0;
    #pragma unroll
    for (int i = 0; i < 16; ++i) {
      int ci = s_wtot[i];
      if (i < w) off += ci;
      tot += ci;
    }
    if (v) {
      int pos = running + off + __popcll(bl & ((1ull << lane) - 1ull));
      c2_sc[(size_t)bc * MSEL + pos] = sc[k];
      reinterpret_cast<float4*>(c2_bx)[(size_t)bc * MSEL + pos] =
          reinterpret_cast<const float4*>(cand_bx)[(size_t)bc * CAP + j];
    }
    running += tot;
    __syncthreads();
  }
  if (t == 0) {
    kcnt[bc] = running;
    thrv[bc] = (T == 0) ? -1e30f : __int_as_float(s_thrbits);
  }
}

// ---------------- K5: single-wave soft-NMS per (b,c) over the reduced set ----------------
__global__ __launch_bounds__(64) void k_nms1w(
    const float* __restrict__ c2_sc, const float* __restrict__ c2_bx,
    const int* __restrict__ kcnt, const float* __restrict__ thrv,
    float* __restrict__ out_box, float* __restrict__ out_sc, int* __restrict__ out_pick,
    int* __restrict__ flagOK)
{
  #pragma clang fp contract(off)
  const int bc = blockIdx.x;
  const int lane = threadIdx.x;

  __shared__ float4 sb_[MSEL];
  const int KM = kcnt[bc];
  const float thr = thrv[bc];

  float  rsc[NSLOT];
  float4 rbx[NSLOT];
  float  rar[NSLOT];
  #pragma unroll
  for (int s = 0; s < NSLOT; ++s) {
    int p = s * 64 + lane;
    if (p < KM) {
      rsc[s] = c2_sc[(size_t)bc * MSEL + p];
      float4 bb = reinterpret_cast<const float4*>(c2_bx)[(size_t)bc * MSEL + p];
      rbx[s] = bb;
      sb_[p] = bb;
      rar[s] = (bb.z - bb.x) * (bb.w - bb.y);
    } else {
      rsc[s] = NEGF;
      rbx[s].x = rbx[s].y = rbx[s].z = rbx[s].w = 0.0f;
      float4 z; z.x = z.y = z.z = z.w = 0.0f;
      sb_[p] = z;
      rar[s] = 0.0f;
    }
  }
  __syncthreads();

  float* ob  = out_box  + (size_t)bc * TDET * 4;
  float* osc = out_sc   + (size_t)bc * TDET;
  int*   opk = out_pick + (size_t)bc * TDET;

  bool ok = true, early = false;
  int total = 0;
  for (int iter = 0; iter < TDET; ++iter) {
    float bs = rsc[0]; int bp = lane;           // p = 0*64 + lane
    #pragma unroll
    for (int s = 1; s < NSLOT; ++s)
      if (rsc[s] > bs) { bs = rsc[s]; bp = s * 64 + lane; }  // strict > => lowest p
    wave_comb64(bs, bp);
    const float ms = rl_f(bs, 63);
    const int   mj = __builtin_amdgcn_readlane(bp, 63);
    if (ms < CONF_T) { early = true; break; }
    ok = ok && (ms > thr);                      // exactness guard vs excluded set

    float4 pb = sb_[mj];                        // uniform broadcast read
    if (lane == 0) {
      ob[iter * 4 + 0] = pb.x; ob[iter * 4 + 1] = pb.y;
      ob[iter * 4 + 2] = pb.z; ob[iter * 4 + 3] = pb.w;
      osc[iter] = ms; opk[iter] = 1;
    }
    total = iter + 1;
    float pa = (pb.z - pb.x) * (pb.w - pb.y);
    #pragma unroll
    for (int s = 0; s < NSLOT; ++s) {
      float sv = rsc[s];
      if (sv == NEGF) continue;
      int p = s * 64 + lane;
      if (p == mj) { rsc[s] = NEGF; continue; }
      float4 bb = rbx[s];
      // exact zero-intersection reject (inter==0 => score bit-identical)
      if (pb.x > bb.z || pb.z < bb.x || pb.y > bb.w || pb.w < bb.y) continue;
      float ltx = fmaxf(pb.x, bb.x);
      float lty = fmaxf(pb.y, bb.y);
      float rbv = fminf(pb.z, bb.z);
      float rby = fminf(pb.w, bb.w);
      float wx = fmaxf(rbv - ltx, 0.0f);
      float wy = fmaxf(rby - lty, 0.0f);
      float inter = wx * wy;
      if (inter > 0.0f) {
        float iou = inter / ((pa + rar[s]) - inter);
        float ns;
        if (iou > 0.5f) ns = NEGF;
        else {
          ns = sv * expf((-10.0f * iou) * iou);
          if (ns < CONF_T) ns = NEGF;           // pruning: output-equivalent
        }
        rsc[s] = ns;
      }
    }
  }
  if (early) ok = ok && (thr < CONF_T);
  for (int r = total + lane; r < TDET; r += 64) opk[r] = 0;
  if (lane == 0) flagOK[bc] = ok ? 1 : 0;
}

// ---------------- K6: repair — round-8 exact batched NMS, gated on flag ----------------
__global__ __launch_bounds__(1024) void k_nms_full(
    const float* __restrict__ cand_sc, const float* __restrict__ cand_bx,
    const int* __restrict__ ktot, const int* __restrict__ flagOK,
    float* __restrict__ out_box, float* __restrict__ out_sc, int* __restrict__ out_pick)
{
  #pragma clang fp contract(off)
  const int bc = blockIdx.x;
  if (flagOK[bc]) return;
  const int t = threadIdx.x;
  const int lane = t & 63, w = t >> 6;

  __shared__ float4 s_box[CAP];
  __shared__ float  pub_s[64];
  __shared__ int    pub_j[64];
  __shared__ int    s_pkj[TDET];
  __shared__ float  s_pks[TDET];
  __shared__ int    s_info[2];

  int K = ktot[bc]; if (K > CAP) K = CAP;

  float  rsc[4];
  float4 rbx[4];
  float  rar[4];
  #pragma unroll
  for (int k = 0; k < 4; ++k) {
    int j = k * 1024 + t;
    if (j < K) {
      rsc[k] = cand_sc[(size_t)bc * CAP + j];
      float4 bb = reinterpret_cast<const float4*>(cand_bx)[(size_t)bc * CAP + j];
      rbx[k] = bb;
      s_box[j] = bb;
      rar[k] = (bb.z - bb.x) * (bb.w - bb.y);
    } else {
      rsc[k] = NEGF;
      rbx[k].x = rbx[k].y = rbx[k].z = rbx[k].w = 0.0f;
      float4 z; z.x = z.y = z.z = z.w = 0.0f;
      s_box[j] = z;
      rar[k] = 0.0f;
    }
  }

  auto publish4 = [&]() {
    float a0 = rsc[0], a1 = rsc[1], a2 = rsc[2], a3 = rsc[3];
    #pragma unroll
    for (int r = 0; r < 4; ++r) {
      float bs = a0; int bk = 0;
      if (a1 > bs) { bs = a1; bk = 1; }
      if (a2 > bs) { bs = a2; bk = 2; }
      if (a3 > bs) { bs = a3; bk = 3; }
      float s1 = bs; int j1 = bk * 1024 + t;
      wave_comb64(s1, j1);
      int ju = __builtin_amdgcn_readlane(j1, 63);
      if ((ju & 1023) == t) {
        int ex = ju >> 10;
        if (ex == 0) a0 = NEGF; else if (ex == 1) a1 = NEGF;
        else if (ex == 2) a2 = NEGF; else a3 = NEGF;
      }
      if (lane == 63) { pub_s[w * 4 + r] = s1; pub_j[w * 4 + r] = j1; }
    }
  };

  publish4();

  int total = 0;
  while (true) {
    __syncthreads();
    if (w == 0) {
      float es = pub_s[lane];
      int   ej = pub_j[lane];
      float4 eb = s_box[ej];
      float ear = (eb.z - eb.x) * (eb.w - eb.y);
      bool  eav = (es >= CONF_T);
      float hv = ((lane & 3) == 3) ? es : NEGF;
      wave_fmax64(hv);
      const float H = rl_f(hv, 63);
      int Rr = 0, dn = 0;
      while (true) {
        float cs = eav ? es : NEGF;
        int   cj = eav ? ej : 0x7fffffff;
        wave_comb64(cs, cj);
        float ms = rl_f(cs, 63);
        int   mj = __builtin_amdgcn_readlane(cj, 63);
        if (ms < CONF_T) { if (H < CONF_T) dn = 1; break; }
        if (Rr > 0 && !(ms > H)) break;
        if (lane == 0) { s_pkj[total + Rr] = mj; s_pks[total + Rr] = ms; }
        Rr++;
        if (total + Rr >= TDET) { dn = 1; break; }
        float4 pb = s_box[mj];
        float pa = (pb.z - pb.x) * (pb.w - pb.y);
        if (eav) {
          if (ej == mj) { eav = false; }
          else {
            float ltx = fmaxf(pb.x, eb.x);
            float lty = fmaxf(pb.y, eb.y);
            float rbv = fminf(pb.z, eb.z);
            float rby = fminf(pb.w, eb.w);
            float wx = fmaxf(rbv - ltx, 0.0f);
            float wy = fmaxf(rby - lty, 0.0f);
            float inter = wx * wy;
            if (inter > 0.0f) {
              float iou = inter / ((pa + ear) - inter);
              if (iou > 0.5f) { eav = false; }
              else {
                es = es * expf((-10.0f * iou) * iou);
                if (es < CONF_T) eav = false;
              }
            }
          }
        }
      }
      if (lane == 0) { s_info[0] = Rr; s_info[1] = dn; }
    }
    __syncthreads();

    const int Rr = s_info[0];
    const int dn = s_info[1];
    for (int r = 0; r < Rr; ++r) {
      const int jp = s_pkj[total + r];
      float4 pb = s_box[jp];
      float pa = (pb.z - pb.x) * (pb.w - pb.y);
      #pragma unroll
      for (int k = 0; k < 4; ++k) {
        float s = rsc[k];
        if (s == NEGF) continue;
        if (k * 1024 + t == jp) { rsc[k] = NEGF; continue; }
        float ltx = fmaxf(pb.x, rbx[k].x);
        float lty = fmaxf(pb.y, rbx[k].y);
        float rbv = fminf(pb.z, rbx[k].z);
        float rby = fminf(pb.w, rbx[k].w);
        float wx = fmaxf(rbv - ltx, 0.0f);
        float wy = fmaxf(rby - lty, 0.0f);
        float inter = wx * wy;
        if (inter > 0.0f) {
          float iou = inter / ((pa + rar[k]) - inter);
          float ns;
          if (iou > 0.5f) ns = NEGF;
          else {
            ns = s * expf((-10.0f * iou) * iou);
            if (ns < CONF_T) ns = NEGF;
          }
          rsc[k] = ns;
        }
      }
    }
    total += Rr;
    if (dn) break;
    publish4();
  }

  float* ob  = out_box  + (size_t)bc * TDET * 4;
  float* osc = out_sc   + (size_t)bc * TDET;
  int*   opk = out_pick + (size_t)bc * TDET;
  if (t < TDET) {
    if (t < total) {
      int jp = s_pkj[t];
      float4 pb = s_box[jp];
      ob[t * 4 + 0] = pb.x; ob[t * 4 + 1] = pb.y;
      ob[t * 4 + 2] = pb.z; ob[t * 4 + 3] = pb.w;
      osc[t] = s_pks[t];
      opk[t] = 1;
    } else {
      opk[t] = 0;
    }
  }
}

// ---------------- K7: per-batch compaction + stable top-100 (bitonic) ----------------
__global__ __launch_bounds__(1024) void k_post(
    const float* __restrict__ out_box, const float* __restrict__ out_sc,
    const int* __restrict__ out_pick,
    float* __restrict__ out, int B)
{
  #pragma clang fp contract(off)
  const int b = blockIdx.x;
  const int t = threadIdx.x;

  __shared__ float p_sc[MTOT];
  __shared__ float p_bx[MTOT * 4];
  __shared__ unsigned char p_v[MTOT];
  __shared__ float q_sc[MTOT];
  __shared__ short q_m[MTOT];
  __shared__ int s_wtot[16];
  __shared__ unsigned long long s_key[2048];

  for (int m = t; m < MTOT; m += 1024) {
    int c = m / TDET, tt = m % TDET;
    int lanebc = b * NCLS + c;
    int pk = out_pick[(size_t)lanebc * TDET + tt];
    p_v[m] = (unsigned char)pk;
    if (pk) {
      p_sc[m] = out_sc[(size_t)lanebc * TDET + tt];
      p_bx[m * 4 + 0] = out_box[((size_t)lanebc * TDET + tt) * 4 + 0];
      p_bx[m * 4 + 1] = out_box[((size_t)lanebc * TDET + tt) * 4 + 1];
      p_bx[m * 4 + 2] = out_box[((size_t)lanebc * TDET + tt) * 4 + 2];
      p_bx[m * 4 + 3] = out_box[((size_t)lanebc * TDET + tt) * 4 + 3];
    } else {
      p_sc[m] = 0.0f;
      p_bx[m * 4 + 0] = 0.0f; p_bx[m * 4 + 1] = 0.0f;
      p_bx[m * 4 + 2] = 0.0f; p_bx[m * 4 + 3] = 0.0f;
    }
  }
  __syncthreads();

  int running = 0;
  for (int base = 0; base < MTOT; base += 1024) {
    int m = base + t;
    bool v = (m < MTOT) && p_v[m];
    unsigned long long ball = __ballot(v);
    int lane = t & 63, w = t >> 6;
    if (lane == 0) s_wtot[w] = __popcll(ball);
    __syncthreads();
    int off = 0, tot = 0;
    #pragma unroll
    for (int i = 0; i < 16; ++i) {
      int ci = s_wtot[i];
      if (i < w) off += ci;
      tot += ci;
    }
    if (v) {
      int wpre = __popcll(ball & ((1ull << lane) - 1ull));
      int j = running + off + wpre;
      q_sc[j] = p_sc[m];
      q_m[j] = (short)m;
    }
    running += tot;
    __syncthreads();
  }
  int nv = running;
  bool over = nv > TDET;

  if (over) {
    for (int e = t; e < 2048; e += 1024) {
      unsigned long long kk = 0;
      if (e < nv) {
        unsigned int sb = __float_as_uint(q_sc[e]);
        kk = ((unsigned long long)sb << 32) | (unsigned int)(~e);
      }
      s_key[e] = ~kk;
    }
    for (int kk2 = 2; kk2 <= 2048; kk2 <<= 1) {
      for (int j = kk2 >> 1; j > 0; j >>= 1) {
        __syncthreads();
        int e = ((t & ~(j - 1)) << 1) | (t & (j - 1));
        int q = e | j;
        unsigned long long a = s_key[e], bb = s_key[q];
        bool up = ((e & kk2) == 0);
        bool sw = up ? (a > bb) : (a < bb);
        if (sw) { s_key[e] = bb; s_key[q] = a; }
      }
    }
    __syncthreads();
  }

  int vd = nv < TDET ? nv : TDET;
  int base_box = B;
  int base_sc  = B + B * TDET * 4;
  int base_cl  = base_sc + B * TDET;
  if (t == 0) out[b] = (float)vd;
  if (t < TDET) {
    float sc = 0.0f, cl = -1.0f, b0 = 0.0f, b1 = 0.0f, b2 = 0.0f, b3 = 0.0f;
    int p = -1;
    if (t < nv) p = over ? (int)(unsigned int)s_key[t] : t;
    if (p >= 0) {
      int m = q_m[p];
      sc = q_sc[p];
      cl = (float)(m / TDET);
      b0 = p_bx[m * 4 + 0]; b1 = p_bx[m * 4 + 1];
      b2 = p_bx[m * 4 + 2]; b3 = p_bx[m * 4 + 3];
    }
    int o = b * TDET + t;
    out[base_box + o * 4 + 0] = b0;
    out[base_box + o * 4 + 1] = b1;
    out[base_box + o * 4 + 2] = b2;
    out[base_box + o * 4 + 3] = b3;
    out[base_sc + o] = sc;
    out[base_cl + o] = cl;
  }
}

extern "C" void kernel_launch(void* const* d_in, const int* in_sizes, int n_in,
                              void* d_out, int out_size, void* d_ws, size_t ws_size,
                              hipStream_t stream) {
  const float* pred = (const float*)d_in[0];
  const float* anch = (const float*)d_in[1];
  int N  = in_sizes[1] / 4;       // 49104
  int BN = in_sizes[0] / 20;      // B*N
  int B  = BN / N;                // 4
  int nchunk = (N + 255) / 256;   // 192
  int NBC = B * NCLS;             // 64

  char* ws = (char*)d_ws;
  size_t off = 0;
  // float4-accessed arrays first (16B alignment)
  float* boxes  = (float*)(ws + off); off += (size_t)BN * 4 * sizeof(float);
  float* candbx = (float*)(ws + off); off += (size_t)NBC * CAP * 4 * sizeof(float);
  float* c2bx   = (float*)(ws + off); off += (size_t)NBC * MSEL * 4 * sizeof(float);
  float* obox   = (float*)(ws + off); off += (size_t)NBC * TDET * 4 * sizeof(float);
  float* score  = (float*)(ws + off); off += (size_t)BN * sizeof(float);
  float* candsc = (float*)(ws + off); off += (size_t)NBC * CAP * sizeof(float);
  float* c2sc   = (float*)(ws + off); off += (size_t)NBC * MSEL * sizeof(float);
  float* osc    = (float*)(ws + off); off += (size_t)NBC * TDET * sizeof(float);
  float* thrv   = (float*)(ws + off); off += (size_t)NBC * sizeof(float);
  int*   cls    = (int*)(ws + off);   off += (size_t)BN * sizeof(int);
  int*   counts = (int*)(ws + off);   off += (size_t)NBC * nchunk * sizeof(int);
  int*   offs   = (int*)(ws + off);   off += (size_t)NBC * nchunk * sizeof(int);
  int*   ktot   = (int*)(ws + off);   off += (size_t)NBC * sizeof(int);
  int*   kcnt   = (int*)(ws + off);   off += (size_t)NBC * sizeof(int);
  int*   opick  = (int*)(ws + off);   off += (size_t)NBC * TDET * sizeof(int);
  int*   flagOK = (int*)(ws + off);   off += (size_t)NBC * sizeof(int);

  k_decode<<<B * nchunk, 256, 0, stream>>>(pred, anch, boxes, score, cls, counts, N, nchunk);
  k_scan<<<NBC, 256, 0, stream>>>(counts, offs, ktot, nchunk);
  k_scatter<<<B * nchunk, 256, 0, stream>>>(score, cls, boxes, offs, candsc, candbx, N, nchunk);
  k_select<<<NBC, 1024, 0, stream>>>(candsc, candbx, ktot, c2sc, c2bx, kcnt, thrv);
  k_nms1w<<<NBC, 64, 0, stream>>>(c2sc, c2bx, kcnt, thrv, obox, osc, opick, flagOK);
  k_nms_full<<<NBC, 1024, 0, stream>>>(candsc, candbx, ktot, flagOK, obox, osc, opick);
  k_post<<<B, 1024, 0, stream>>>(obox, osc, opick, (float*)d_out, B);
}

// Round 10
// 187.367 us; speedup vs baseline: 1.6221x; 1.6221x over previous
//
#include <hip/hip_runtime.h>
#include <math.h>

#define CONF_T 0.05f
#define NEGF  -1e10f
#define NCLS 16
#define TDET 100
#define CAP 4096
#define MSEL 640
#define MTOT (NCLS*TDET)    // 1600

// DPP-based combine: (max score, tie -> min j). Lattice op: associative,
// commutative, idempotent => over-inclusive row masks / self-combine safe.
template<int CTRL>
__device__ __forceinline__ void dpp_comb(float& s, int& j) {
  int si_ = __builtin_amdgcn_update_dpp(__float_as_int(s), __float_as_int(s),
                                        CTRL, 0xf, 0xf, false);
  int ji_ = __builtin_amdgcn_update_dpp(j, j, CTRL, 0xf, 0xf, false);
  float si = __int_as_float(si_);
  bool take = (si > s) || (si == s && ji_ < j);
  s = take ? si : s;
  j = take ? ji_ : j;
}
template<int CTRL>
__device__ __forceinline__ void dpp_max1(float& s) {
  int si_ = __builtin_amdgcn_update_dpp(__float_as_int(s), __float_as_int(s),
                                        CTRL, 0xf, 0xf, false);
  s = fmaxf(s, __int_as_float(si_));
}
#define ROW_SHR1  0x111
#define ROW_SHR2  0x112
#define ROW_SHR4  0x114
#define ROW_SHR8  0x118
#define ROW_BC15  0x142
#define ROW_BC31  0x143

__device__ __forceinline__ void wave_comb64(float& s, int& j) {
  dpp_comb<ROW_SHR1>(s, j);
  dpp_comb<ROW_SHR2>(s, j);
  dpp_comb<ROW_SHR4>(s, j);
  dpp_comb<ROW_SHR8>(s, j);
  dpp_comb<ROW_BC15>(s, j);
  dpp_comb<ROW_BC31>(s, j);
}
__device__ __forceinline__ void wave_fmax64(float& s) {
  dpp_max1<ROW_SHR1>(s);
  dpp_max1<ROW_SHR2>(s);
  dpp_max1<ROW_SHR4>(s);
  dpp_max1<ROW_SHR8>(s);
  dpp_max1<ROW_BC15>(s);
  dpp_max1<ROW_BC31>(s);
}
__device__ __forceinline__ float rl_f(float v, int l) {
  return __int_as_float(__builtin_amdgcn_readlane(__float_as_int(v), l));
}

// ---------------- K1: decode boxes + class/score + per-chunk class counts ----------------
__global__ __launch_bounds__(256) void k_decode(
    const float* __restrict__ pred, const float* __restrict__ anch,
    float* __restrict__ boxes, float* __restrict__ score, int* __restrict__ cls,
    int* __restrict__ counts, int N, int nchunk)
{
  #pragma clang fp contract(off)
  const int b = blockIdx.x / nchunk;
  const int chunk = blockIdx.x % nchunk;
  const int t = threadIdx.x;
  const int n = chunk * 256 + t;

  __shared__ int hist[NCLS];
  if (t < NCLS) hist[t] = 0;
  __syncthreads();

  int v = -1;
  if (n < N) {
    const size_t i = (size_t)b * N + n;
    const float4* p4 = reinterpret_cast<const float4*>(pred + i * 20);
    float4 v0 = p4[0], v1 = p4[1], v2 = p4[2], v3 = p4[3], v4 = p4[4];
    float4 a = reinterpret_cast<const float4*>(anch)[n];  // cx, cy, w, h
    float xx = v0.x * a.z + a.x;
    float yy = v0.y * a.w + a.y;
    float wx = expf(v0.z) * a.z;
    float wy = expf(v0.w) * a.w;
    float hx = 0.5f * wx, hy = 0.5f * wy;
    float4 bx;
    bx.x = xx - hx; bx.y = yy - hy; bx.z = xx + hx; bx.w = yy + hy;
    reinterpret_cast<float4*>(boxes)[i] = bx;

    float lg[NCLS] = {v1.x, v1.y, v1.z, v1.w, v2.x, v2.y, v2.z, v2.w,
                      v3.x, v3.y, v3.z, v3.w, v4.x, v4.y, v4.z, v4.w};
    float best = -1.0f; int bi = 0;
    #pragma unroll
    for (int c = 0; c < NCLS; ++c) {
      float s = 1.0f / (1.0f + expf(-lg[c]));
      if (s > best) { best = s; bi = c; }
    }
    score[i] = best;
    v = (best >= CONF_T) ? bi : -1;
    cls[i] = v;
  }

  int lane = t & 63;
  #pragma unroll
  for (int c = 0; c < NCLS; ++c) {
    unsigned long long bl = __ballot(v == c);
    if (lane == 0 && bl) atomicAdd(&hist[c], __popcll(bl));
  }
  __syncthreads();
  if (t < NCLS) counts[(b * NCLS + t) * nchunk + chunk] = hist[t];
}

// ---------------- K2: per-(b,c) exclusive scan over chunk counts ----------------
__global__ __launch_bounds__(256) void k_scan(
    const int* __restrict__ counts, int* __restrict__ offs, int* __restrict__ ktot,
    int nchunk)
{
  const int bc = blockIdx.x;
  const int t = threadIdx.x;
  __shared__ int c_[256];
  __shared__ int o_[257];
  if (t < nchunk) c_[t] = counts[bc * nchunk + t];
  __syncthreads();
  if (t == 0) {
    int run = 0;
    for (int i = 0; i < nchunk; ++i) { o_[i] = run; run += c_[i]; }
    o_[nchunk] = run;
  }
  __syncthreads();
  if (t < nchunk) offs[bc * nchunk + t] = o_[t];
  if (t == 0) ktot[bc] = o_[nchunk];
}

// ---------------- K3: stable parallel scatter into per-(b,c) candidate lists ----------------
__global__ __launch_bounds__(256) void k_scatter(
    const float* __restrict__ score, const int* __restrict__ cls,
    const float* __restrict__ boxes, const int* __restrict__ offs,
    float* __restrict__ cand_sc, float* __restrict__ cand_bx,
    int N, int nchunk)
{
  const int b = blockIdx.x / nchunk;
  const int chunk = blockIdx.x % nchunk;
  const int t = threadIdx.x;
  const int n = chunk * 256 + t;

  __shared__ int wcnt[4][NCLS];
  int v = (n < N) ? cls[(size_t)b * N + n] : -1;
  int lane = t & 63, w = t >> 6;
  int myrank = 0;
  #pragma unroll
  for (int c = 0; c < NCLS; ++c) {
    unsigned long long bl = __ballot(v == c);
    if (lane == 0) wcnt[w][c] = __popcll(bl);
    if (v == c) myrank = __popcll(bl & ((1ull << lane) - 1ull));
  }
  __syncthreads();
  if (v >= 0) {
    int pre = 0;
    #pragma unroll
    for (int i = 0; i < 4; ++i) if (i < w) pre += wcnt[i][v];
    int pos = offs[(b * NCLS + v) * nchunk + chunk] + pre + myrank;
    if (pos < CAP) {
      int bc = b * NCLS + v;
      cand_sc[(size_t)bc * CAP + pos] = score[(size_t)b * N + n];
      reinterpret_cast<float4*>(cand_bx)[(size_t)bc * CAP + pos] =
          reinterpret_cast<const float4*>(boxes)[(size_t)b * N + n];
    }
  }
}

// ---------------- K4: per-(b,c) top-MSEL selection (whole quantization bins) ----------------
// Keeps all entries whose score-bin >= T where T = min bin with cntGE(T) <= MSEL.
// thr = max excluded score (strictly below every kept score's bin). Order kept.
__global__ __launch_bounds__(1024) void k_select(
    const float* __restrict__ cand_sc, const float* __restrict__ cand_bx,
    const int* __restrict__ ktot,
    float* __restrict__ c2_sc, float* __restrict__ c2_bx,
    int* __restrict__ kcnt, float* __restrict__ thrv)
{
  const int bc = blockIdx.x;
  const int t = threadIdx.x;
  __shared__ int hist[4096];
  __shared__ int ss[1024];
  __shared__ int s_T;
  __shared__ int s_thrbits;
  __shared__ int s_wtot[16];

  int K = ktot[bc]; if (K > CAP) K = CAP;
  for (int i = t; i < 4096; i += 1024) hist[i] = 0;
  if (t == 0) { s_T = 4096; s_thrbits = 0; }
  __syncthreads();

  float sc[4]; int key[4];
  #pragma unroll
  for (int k = 0; k < 4; ++k) {
    int j = k * 1024 + t;
    if (j < K) {
      sc[k] = cand_sc[(size_t)bc * CAP + j];
      int bits = __float_as_int(sc[k]);
      int kk = (bits >> 11) - 0x7E000;          // [0.5,1.0) -> 0..4095, monotone
      kk = kk < 0 ? 0 : (kk > 4095 ? 4095 : kk);
      key[k] = kk;
      atomicAdd(&hist[kk], 1);
    } else { key[k] = -1; sc[k] = 0.0f; }
  }
  __syncthreads();

  int loc = hist[4 * t] + hist[4 * t + 1] + hist[4 * t + 2] + hist[4 * t + 3];
  ss[t] = loc;
  __syncthreads();
  for (int d = 1; d < 1024; d <<= 1) {
    int v = ss[t];
    int a = (t + d < 1024) ? ss[t + d] : 0;
    __syncthreads();
    ss[t] = v + a;
    __syncthreads();
  }
  {
    int h0 = hist[4 * t], h1 = hist[4 * t + 1], h2 = hist[4 * t + 2];
    int c0 = ss[t];           // cntGE(4t)
    int c1 = c0 - h0, c2v = c1 - h1, c3 = c2v - h2;
    int cand = 0x7fffffff;
    if      (c0  <= MSEL) cand = 4 * t;
    else if (c1  <= MSEL) cand = 4 * t + 1;
    else if (c2v <= MSEL) cand = 4 * t + 2;
    else if (c3  <= MSEL) cand = 4 * t + 3;
    if (cand != 0x7fffffff) atomicMin(&s_T, cand);
  }
  __syncthreads();
  const int T = s_T;
  #pragma unroll
  for (int k = 0; k < 4; ++k)
    if (key[k] >= 0 && key[k] < T) atomicMax(&s_thrbits, __float_as_int(sc[k]));
  __syncthreads();

  // stable compaction of kept entries (order preserved)
  int running = 0;
  #pragma unroll
  for (int k = 0; k < 4; ++k) {
    int j = k * 1024 + t;
    bool v = (key[k] >= 0) && (key[k] >= T);
    unsigned long long bl = __ballot(v);
    int lane = t & 63, w = t >> 6;
    if (lane == 0) s_wtot[w] = __popcll(bl);
    __syncthreads();
    int off = 0, tot = 0;
    #pragma unroll
    for (int i = 0; i < 16; ++i) {
      int ci = s_wtot[i];
      if (i < w) off += ci;
      tot += ci;
    }
    if (v) {
      int pos = running + off + __popcll(bl & ((1ull << lane) - 1ull));
      c2_sc[(size_t)bc * MSEL + pos] = sc[k];
      reinterpret_cast<float4*>(c2_bx)[(size_t)bc * MSEL + pos] =
          reinterpret_cast<const float4*>(cand_bx)[(size_t)bc * CAP + j];
    }
    running += tot;
    __syncthreads();
  }
  if (t == 0) {
    kcnt[bc] = running;
    thrv[bc] = (T == 0) ? -1e30f : __int_as_float(s_thrbits);
  }
}

// ---------------- K5: 4-wave soft-NMS per (b,c) over the reduced set ----------------
// 256 threads, 3 slots/thread (covers MSEL=640 <= 768). Parity-buffered wave
// keys -> ONE barrier per iteration. Exact tie-break: p = s*256+t preserves
// compacted (anchor) order; strict > local argmax + (max s, min p) lattice.
__global__ __launch_bounds__(256) void k_nms4w(
    const float* __restrict__ c2_sc, const float* __restrict__ c2_bx,
    const int* __restrict__ kcnt, const float* __restrict__ thrv,
    float* __restrict__ out_box, float* __restrict__ out_sc, int* __restrict__ out_pick,
    int* __restrict__ flagOK)
{
  #pragma clang fp contract(off)
  const int bc = blockIdx.x;
  const int t = threadIdx.x;
  const int lane = t & 63, w = t >> 6;

  __shared__ float4 sbx[768];
  __shared__ float  s_ks[2][4];
  __shared__ int    s_kj[2][4];

  const int KM = kcnt[bc];
  const float thr = thrv[bc];

  float  rsc[3];
  float4 rbx[3];
  float  rar[3];
  #pragma unroll
  for (int s = 0; s < 3; ++s) {
    int p = s * 256 + t;
    if (p < KM) {
      rsc[s] = c2_sc[(size_t)bc * MSEL + p];
      float4 bb = reinterpret_cast<const float4*>(c2_bx)[(size_t)bc * MSEL + p];
      rbx[s] = bb;
      sbx[p] = bb;
      rar[s] = (bb.z - bb.x) * (bb.w - bb.y);
    } else {
      rsc[s] = NEGF;
      rbx[s].x = rbx[s].y = rbx[s].z = rbx[s].w = 0.0f;
      float4 z; z.x = z.y = z.z = z.w = 0.0f;
      sbx[p] = z;
      rar[s] = 0.0f;
    }
  }
  // publish parity 0
  {
    float bs = rsc[0]; int bp = t;
    if (rsc[1] > bs) { bs = rsc[1]; bp = 256 + t; }   // strict > => lowest s => lowest p
    if (rsc[2] > bs) { bs = rsc[2]; bp = 512 + t; }
    wave_comb64(bs, bp);
    if (lane == 63) { s_ks[0][w] = bs; s_kj[0][w] = bp; }
  }

  float* ob  = out_box  + (size_t)bc * TDET * 4;
  float* osc = out_sc   + (size_t)bc * TDET;
  int*   opk = out_pick + (size_t)bc * TDET;

  bool ok = true, early = false;
  int total = 0;
  for (int iter = 0; iter < TDET; ++iter) {
    __syncthreads();                       // the ONLY barrier per iteration
    const int par = iter & 1;

    // cross-wave combine of the 4 wave keys: lanes 0..3 hold them; 2 DPP steps
    float sv = s_ks[par][lane & 3];
    int   jv = s_kj[par][lane & 3];
    dpp_comb<ROW_SHR1>(sv, jv);
    dpp_comb<ROW_SHR2>(sv, jv);
    const float ms = rl_f(sv, 3);
    const int   mj = __builtin_amdgcn_readlane(jv, 3);
    if (ms < CONF_T) { early = true; break; }
    ok = ok && (ms > thr);                 // exactness guard vs excluded set

    float4 pb = sbx[mj];                   // uniform broadcast read
    if (t == 0) {
      ob[iter * 4 + 0] = pb.x; ob[iter * 4 + 1] = pb.y;
      ob[iter * 4 + 2] = pb.z; ob[iter * 4 + 3] = pb.w;
      osc[iter] = ms; opk[iter] = 1;
    }
    total = iter + 1;
    float pa = (pb.z - pb.x) * (pb.w - pb.y);

    #pragma unroll
    for (int s = 0; s < 3; ++s) {
      float sv2 = rsc[s];
      if (sv2 == NEGF) continue;
      int p = s * 256 + t;
      if (p == mj) { rsc[s] = NEGF; continue; }
      float4 bb = rbx[s];
      // exact zero-intersection reject (inter==0 => score bit-identical)
      if (pb.x > bb.z || pb.z < bb.x || pb.y > bb.w || pb.w < bb.y) continue;
      float ltx = fmaxf(pb.x, bb.x);
      float lty = fmaxf(pb.y, bb.y);
      float rbv = fminf(pb.z, bb.z);
      float rby = fminf(pb.w, bb.w);
      float wx = fmaxf(rbv - ltx, 0.0f);
      float wy = fmaxf(rby - lty, 0.0f);
      float inter = wx * wy;
      if (inter > 0.0f) {
        float iou = inter / ((pa + rar[s]) - inter);
        float ns;
        if (iou > 0.5f) ns = NEGF;
        else {
          ns = sv2 * expf((-10.0f * iou) * iou);
          if (ns < CONF_T) ns = NEGF;      // pruning: output-equivalent
        }
        rsc[s] = ns;
      }
    }

    // publish next parity
    float bs = rsc[0]; int bp = t;
    if (rsc[1] > bs) { bs = rsc[1]; bp = 256 + t; }
    if (rsc[2] > bs) { bs = rsc[2]; bp = 512 + t; }
    wave_comb64(bs, bp);
    if (lane == 63) { s_ks[par ^ 1][w] = bs; s_kj[par ^ 1][w] = bp; }
  }
  if (early) ok = ok && (thr < CONF_T);
  for (int r = total + t; r < TDET; r += 256) opk[r] = 0;
  if (t == 0) flagOK[bc] = ok ? 1 : 0;
}

// ---------------- K6: repair — round-8 exact batched NMS, gated on flag ----------------
__global__ __launch_bounds__(1024) void k_nms_full(
    const float* __restrict__ cand_sc, const float* __restrict__ cand_bx,
    const int* __restrict__ ktot, const int* __restrict__ flagOK,
    float* __restrict__ out_box, float* __restrict__ out_sc, int* __restrict__ out_pick)
{
  #pragma clang fp contract(off)
  const int bc = blockIdx.x;
  if (flagOK[bc]) return;
  const int t = threadIdx.x;
  const int lane = t & 63, w = t >> 6;

  __shared__ float4 s_box[CAP];
  __shared__ float  pub_s[64];
  __shared__ int    pub_j[64];
  __shared__ int    s_pkj[TDET];
  __shared__ float  s_pks[TDET];
  __shared__ int    s_info[2];

  int K = ktot[bc]; if (K > CAP) K = CAP;

  float  rsc[4];
  float4 rbx[4];
  float  rar[4];
  #pragma unroll
  for (int k = 0; k < 4; ++k) {
    int j = k * 1024 + t;
    if (j < K) {
      rsc[k] = cand_sc[(size_t)bc * CAP + j];
      float4 bb = reinterpret_cast<const float4*>(cand_bx)[(size_t)bc * CAP + j];
      rbx[k] = bb;
      s_box[j] = bb;
      rar[k] = (bb.z - bb.x) * (bb.w - bb.y);
    } else {
      rsc[k] = NEGF;
      rbx[k].x = rbx[k].y = rbx[k].z = rbx[k].w = 0.0f;
      float4 z; z.x = z.y = z.z = z.w = 0.0f;
      s_box[j] = z;
      rar[k] = 0.0f;
    }
  }

  auto publish4 = [&]() {
    float a0 = rsc[0], a1 = rsc[1], a2 = rsc[2], a3 = rsc[3];
    #pragma unroll
    for (int r = 0; r < 4; ++r) {
      float bs = a0; int bk = 0;
      if (a1 > bs) { bs = a1; bk = 1; }
      if (a2 > bs) { bs = a2; bk = 2; }
      if (a3 > bs) { bs = a3; bk = 3; }
      float s1 = bs; int j1 = bk * 1024 + t;
      wave_comb64(s1, j1);
      int ju = __builtin_amdgcn_readlane(j1, 63);
      if ((ju & 1023) == t) {
        int ex = ju >> 10;
        if (ex == 0) a0 = NEGF; else if (ex == 1) a1 = NEGF;
        else if (ex == 2) a2 = NEGF; else a3 = NEGF;
      }
      if (lane == 63) { pub_s[w * 4 + r] = s1; pub_j[w * 4 + r] = j1; }
    }
  };

  publish4();

  int total = 0;
  while (true) {
    __syncthreads();
    if (w == 0) {
      float es = pub_s[lane];
      int   ej = pub_j[lane];
      float4 eb = s_box[ej];
      float ear = (eb.z - eb.x) * (eb.w - eb.y);
      bool  eav = (es >= CONF_T);
      float hv = ((lane & 3) == 3) ? es : NEGF;
      wave_fmax64(hv);
      const float H = rl_f(hv, 63);
      int Rr = 0, dn = 0;
      while (true) {
        float cs = eav ? es : NEGF;
        int   cj = eav ? ej : 0x7fffffff;
        wave_comb64(cs, cj);
        float ms = rl_f(cs, 63);
        int   mj = __builtin_amdgcn_readlane(cj, 63);
        if (ms < CONF_T) { if (H < CONF_T) dn = 1; break; }
        if (Rr > 0 && !(ms > H)) break;
        if (lane == 0) { s_pkj[total + Rr] = mj; s_pks[total + Rr] = ms; }
        Rr++;
        if (total + Rr >= TDET) { dn = 1; break; }
        float4 pb = s_box[mj];
        float pa = (pb.z - pb.x) * (pb.w - pb.y);
        if (eav) {
          if (ej == mj) { eav = false; }
          else {
            float ltx = fmaxf(pb.x, eb.x);
            float lty = fmaxf(pb.y, eb.y);
            float rbv = fminf(pb.z, eb.z);
            float rby = fminf(pb.w, eb.w);
            float wx = fmaxf(rbv - ltx, 0.0f);
            float wy = fmaxf(rby - lty, 0.0f);
            float inter = wx * wy;
            if (inter > 0.0f) {
              float iou = inter / ((pa + ear) - inter);
              if (iou > 0.5f) { eav = false; }
              else {
                es = es * expf((-10.0f * iou) * iou);
                if (es < CONF_T) eav = false;
              }
            }
          }
        }
      }
      if (lane == 0) { s_info[0] = Rr; s_info[1] = dn; }
    }
    __syncthreads();

    const int Rr = s_info[0];
    const int dn = s_info[1];
    for (int r = 0; r < Rr; ++r) {
      const int jp = s_pkj[total + r];
      float4 pb = s_box[jp];
      float pa = (pb.z - pb.x) * (pb.w - pb.y);
      #pragma unroll
      for (int k = 0; k < 4; ++k) {
        float s = rsc[k];
        if (s == NEGF) continue;
        if (k * 1024 + t == jp) { rsc[k] = NEGF; continue; }
        float ltx = fmaxf(pb.x, rbx[k].x);
        float lty = fmaxf(pb.y, rbx[k].y);
        float rbv = fminf(pb.z, rbx[k].z);
        float rby = fminf(pb.w, rbx[k].w);
        float wx = fmaxf(rbv - ltx, 0.0f);
        float wy = fmaxf(rby - lty, 0.0f);
        float inter = wx * wy;
        if (inter > 0.0f) {
          float iou = inter / ((pa + rar[k]) - inter);
          float ns;
          if (iou > 0.5f) ns = NEGF;
          else {
            ns = s * expf((-10.0f * iou) * iou);
            if (ns < CONF_T) ns = NEGF;
          }
          rsc[k] = ns;
        }
      }
    }
    total += Rr;
    if (dn) break;
    publish4();
  }

  float* ob  = out_box  + (size_t)bc * TDET * 4;
  float* osc = out_sc   + (size_t)bc * TDET;
  int*   opk = out_pick + (size_t)bc * TDET;
  if (t < TDET) {
    if (t < total) {
      int jp = s_pkj[t];
      float4 pb = s_box[jp];
      ob[t * 4 + 0] = pb.x; ob[t * 4 + 1] = pb.y;
      ob[t * 4 + 2] = pb.z; ob[t * 4 + 3] = pb.w;
      osc[t] = s_pks[t];
      opk[t] = 1;
    } else {
      opk[t] = 0;
    }
  }
}

// ---------------- K7: per-batch compaction + stable top-100 (bitonic) ----------------
__global__ __launch_bounds__(1024) void k_post(
    const float* __restrict__ out_box, const float* __restrict__ out_sc,
    const int* __restrict__ out_pick,
    float* __restrict__ out, int B)
{
  #pragma clang fp contract(off)
  const int b = blockIdx.x;
  const int t = threadIdx.x;

  __shared__ float p_sc[MTOT];
  __shared__ float p_bx[MTOT * 4];
  __shared__ unsigned char p_v[MTOT];
  __shared__ float q_sc[MTOT];
  __shared__ short q_m[MTOT];
  __shared__ int s_wtot[16];
  __shared__ unsigned long long s_key[2048];

  for (int m = t; m < MTOT; m += 1024) {
    int c = m / TDET, tt = m % TDET;
    int lanebc = b * NCLS + c;
    int pk = out_pick[(size_t)lanebc * TDET + tt];
    p_v[m] = (unsigned char)pk;
    if (pk) {
      p_sc[m] = out_sc[(size_t)lanebc * TDET + tt];
      p_bx[m * 4 + 0] = out_box[((size_t)lanebc * TDET + tt) * 4 + 0];
      p_bx[m * 4 + 1] = out_box[((size_t)lanebc * TDET + tt) * 4 + 1];
      p_bx[m * 4 + 2] = out_box[((size_t)lanebc * TDET + tt) * 4 + 2];
      p_bx[m * 4 + 3] = out_box[((size_t)lanebc * TDET + tt) * 4 + 3];
    } else {
      p_sc[m] = 0.0f;
      p_bx[m * 4 + 0] = 0.0f; p_bx[m * 4 + 1] = 0.0f;
      p_bx[m * 4 + 2] = 0.0f; p_bx[m * 4 + 3] = 0.0f;
    }
  }
  __syncthreads();

  int running = 0;
  for (int base = 0; base < MTOT; base += 1024) {
    int m = base + t;
    bool v = (m < MTOT) && p_v[m];
    unsigned long long ball = __ballot(v);
    int lane = t & 63, w = t >> 6;
    if (lane == 0) s_wtot[w] = __popcll(ball);
    __syncthreads();
    int off = 0, tot = 0;
    #pragma unroll
    for (int i = 0; i < 16; ++i) {
      int ci = s_wtot[i];
      if (i < w) off += ci;
      tot += ci;
    }
    if (v) {
      int wpre = __popcll(ball & ((1ull << lane) - 1ull));
      int j = running + off + wpre;
      q_sc[j] = p_sc[m];
      q_m[j] = (short)m;
    }
    running += tot;
    __syncthreads();
  }
  int nv = running;
  bool over = nv > TDET;

  if (over) {
    for (int e = t; e < 2048; e += 1024) {
      unsigned long long kk = 0;
      if (e < nv) {
        unsigned int sb = __float_as_uint(q_sc[e]);
        kk = ((unsigned long long)sb << 32) | (unsigned int)(~e);
      }
      s_key[e] = ~kk;
    }
    for (int kk2 = 2; kk2 <= 2048; kk2 <<= 1) {
      for (int j = kk2 >> 1; j > 0; j >>= 1) {
        __syncthreads();
        int e = ((t & ~(j - 1)) << 1) | (t & (j - 1));
        int q = e | j;
        unsigned long long a = s_key[e], bb = s_key[q];
        bool up = ((e & kk2) == 0);
        bool sw = up ? (a > bb) : (a < bb);
        if (sw) { s_key[e] = bb; s_key[q] = a; }
      }
    }
    __syncthreads();
  }

  int vd = nv < TDET ? nv : TDET;
  int base_box = B;
  int base_sc  = B + B * TDET * 4;
  int base_cl  = base_sc + B * TDET;
  if (t == 0) out[b] = (float)vd;
  if (t < TDET) {
    float sc = 0.0f, cl = -1.0f, b0 = 0.0f, b1 = 0.0f, b2 = 0.0f, b3 = 0.0f;
    int p = -1;
    if (t < nv) p = over ? (int)(unsigned int)s_key[t] : t;
    if (p >= 0) {
      int m = q_m[p];
      sc = q_sc[p];
      cl = (float)(m / TDET);
      b0 = p_bx[m * 4 + 0]; b1 = p_bx[m * 4 + 1];
      b2 = p_bx[m * 4 + 2]; b3 = p_bx[m * 4 + 3];
    }
    int o = b * TDET + t;
    out[base_box + o * 4 + 0] = b0;
    out[base_box + o * 4 + 1] = b1;
    out[base_box + o * 4 + 2] = b2;
    out[base_box + o * 4 + 3] = b3;
    out[base_sc + o] = sc;
    out[base_cl + o] = cl;
  }
}

extern "C" void kernel_launch(void* const* d_in, const int* in_sizes, int n_in,
                              void* d_out, int out_size, void* d_ws, size_t ws_size,
                              hipStream_t stream) {
  const float* pred = (const float*)d_in[0];
  const float* anch = (const float*)d_in[1];
  int N  = in_sizes[1] / 4;       // 49104
  int BN = in_sizes[0] / 20;      // B*N
  int B  = BN / N;                // 4
  int nchunk = (N + 255) / 256;   // 192
  int NBC = B * NCLS;             // 64

  char* ws = (char*)d_ws;
  size_t off = 0;
  // float4-accessed arrays first (16B alignment)
  float* boxes  = (float*)(ws + off); off += (size_t)BN * 4 * sizeof(float);
  float* candbx = (float*)(ws + off); off += (size_t)NBC * CAP * 4 * sizeof(float);
  float* c2bx   = (float*)(ws + off); off += (size_t)NBC * MSEL * 4 * sizeof(float);
  float* obox   = (float*)(ws + off); off += (size_t)NBC * TDET * 4 * sizeof(float);
  float* score  = (float*)(ws + off); off += (size_t)BN * sizeof(float);
  float* candsc = (float*)(ws + off); off += (size_t)NBC * CAP * sizeof(float);
  float* c2sc   = (float*)(ws + off); off += (size_t)NBC * MSEL * sizeof(float);
  float* osc    = (float*)(ws + off); off += (size_t)NBC * TDET * sizeof(float);
  float* thrv   = (float*)(ws + off); off += (size_t)NBC * sizeof(float);
  int*   cls    = (int*)(ws + off);   off += (size_t)BN * sizeof(int);
  int*   counts = (int*)(ws + off);   off += (size_t)NBC * nchunk * sizeof(int);
  int*   offs   = (int*)(ws + off);   off += (size_t)NBC * nchunk * sizeof(int);
  int*   ktot   = (int*)(ws + off);   off += (size_t)NBC * sizeof(int);
  int*   kcnt   = (int*)(ws + off);   off += (size_t)NBC * sizeof(int);
  int*   opick  = (int*)(ws + off);   off += (size_t)NBC * TDET * sizeof(int);
  int*   flagOK = (int*)(ws + off);   off += (size_t)NBC * sizeof(int);

  k_decode<<<B * nchunk, 256, 0, stream>>>(pred, anch, boxes, score, cls, counts, N, nchunk);
  k_scan<<<NBC, 256, 0, stream>>>(counts, offs, ktot, nchunk);
  k_scatter<<<B * nchunk, 256, 0, stream>>>(score, cls, boxes, offs, candsc, candbx, N, nchunk);
  k_select<<<NBC, 1024, 0, stream>>>(candsc, candbx, ktot, c2sc, c2bx, kcnt, thrv);
  k_nms4w<<<NBC, 256, 0, stream>>>(c2sc, c2bx, kcnt, thrv, obox, osc, opick, flagOK);
  k_nms_full<<<NBC, 1024, 0, stream>>>(candsc, candbx, ktot, flagOK, obox, osc, opick);
  k_post<<<B, 1024, 0, stream>>>(obox, osc, opick, (float*)d_out, B);
}